// Round 1
// baseline (188.111 us; speedup 1.0000x reference)
//
#include <hip/hip_runtime.h>
#include <hip/hip_bf16.h>

#define DF 128
#define BSH 5                 // bucket = dst >> 5  (32 nodes / bucket)
#define BNODES 32
#define NBMAX 2048            // max buckets (50000/32 = 1563)
#define PCHUNK 8192           // edges per hist block (prep)
#define BCHUNK 4096           // edges per bin block
#define TILE 2048             // edges per aggregation LDS tile (bucket ~512)
#define ASTRIDE 68            // uints per abuf row (64 data + 4 pad)
#define SRCMASK 0x07ffffffu   // src in low 27 bits, dstLocal in bits 27..31

typedef __attribute__((ext_vector_type(8))) short short8;
typedef __attribute__((ext_vector_type(4))) float floatx4;

__device__ __forceinline__ ushort f2bf(float f) {
    __hip_bfloat16 h = __float2bfloat16(f);   // RNE
    return *reinterpret_cast<ushort*>(&h);
}

// ---------------------------------------------------------------------------
// Fused prep: [0,PH) hist blocks | [PH,PH+64) weight convert | rest x convert.
// Hist blocks merge LDS histograms into global ghist[nb] with device atomics;
// the LAST hist block (done-counter) performs the 1563-entry exclusive scan
// in-kernel (overlapped with the convert blocks), writing gbase/gcur.
// ---------------------------------------------------------------------------
__global__ __launch_bounds__(256) void prep_kernel(
    const float* __restrict__ x, ushort* __restrict__ xbf, int n4,
    const float* __restrict__ W1, const float* __restrict__ W2,
    const float* __restrict__ b1, const float* __restrict__ b2,
    ushort* __restrict__ w1bf, ushort* __restrict__ w2bf, float* __restrict__ bias,
    const int* __restrict__ dst, int* __restrict__ ghist, int* __restrict__ done,
    int* __restrict__ gbase, int* __restrict__ gcur,
    int n_edges, int PH, int nb)
{
    __shared__ int h[NBMAX];
    __shared__ int isLast;
    int bid = blockIdx.x;
    if (bid < PH) {
        for (int j = threadIdx.x; j < nb; j += 256) h[j] = 0;
        __syncthreads();
        int base = bid * PCHUNK;
#pragma unroll 4
        for (int i = 0; i < PCHUNK / 256; ++i) {
            int e = base + i * 256 + threadIdx.x;
            if (e < n_edges) atomicAdd(&h[dst[e] >> BSH], 1);
        }
        __syncthreads();
        for (int j = threadIdx.x; j < nb; j += 256) {
            int c = h[j];
            if (c) atomicAdd(&ghist[j], c);
        }
        __threadfence();            // make this block's ghist atomics visible
        __syncthreads();
        if (threadIdx.x == 0) isLast = (atomicAdd(done, 1) == PH - 1);
        __syncthreads();
        if (isLast) {
            // exclusive scan of ghist[0..nb) by this single block (256 thr x 8)
            int b0 = threadIdx.x * 8;
            int vals[8];
            int s = 0;
#pragma unroll
            for (int k = 0; k < 8; ++k) {
                int idx = b0 + k;
                int v = (idx < nb)
                    ? __hip_atomic_load(&ghist[idx], __ATOMIC_RELAXED,
                                        __HIP_MEMORY_SCOPE_AGENT)
                    : 0;
                vals[k] = v; s += v;
            }
            h[threadIdx.x] = s;
            __syncthreads();
            for (int off = 1; off < 256; off <<= 1) {
                int u = (threadIdx.x >= off) ? h[threadIdx.x - off] : 0;
                __syncthreads();
                h[threadIdx.x] += u;
                __syncthreads();
            }
            int run = h[threadIdx.x] - s;     // exclusive prefix
#pragma unroll
            for (int k = 0; k < 8; ++k) {
                int idx = b0 + k;
                if (idx < nb) { gbase[idx] = run; gcur[idx] = run; run += vals[k]; }
            }
            if (threadIdx.x == 0) gbase[nb] = n_edges;
        }
    } else if (bid < PH + 64) {
        int i = (bid - PH) * 256 + threadIdx.x;
        if (i < DF * DF) {
            w1bf[i] = f2bf(W1[i]);
            w2bf[i] = f2bf(W2[i]);
        }
        if (i < DF) bias[i] = b1[i] + b2[i];
    } else {
        int i = (bid - PH - 64) * 256 + threadIdx.x;
        if (i < n4) {
            float4 v = reinterpret_cast<const float4*>(x)[i];
            ushort4 o;
            o.x = f2bf(v.x); o.y = f2bf(v.y); o.z = f2bf(v.z); o.w = f2bf(v.w);
            reinterpret_cast<ushort4*>(xbf)[i] = o;
        }
    }
}

// ---------------------------------------------------------------------------
// Bin: LDS-histogram this block's BCHUNK edges, reserve a contiguous range in
// each touched bucket via one global atomicAdd on gcur[j], then scatter edges.
// Result: pairs[] is globally BUCKET-CONTIGUOUS (each bucket = one range).
// pairs[p] = src | dstLocal<<27.
// ---------------------------------------------------------------------------
__global__ __launch_bounds__(512) void bin_kernel(
    const int* __restrict__ src, const int* __restrict__ dst,
    int* __restrict__ gcur, uint* __restrict__ pairs, int n_edges, int nb)
{
    __shared__ int h[NBMAX];
    int tid = threadIdx.x;
    for (int j = tid; j < nb; j += 512) h[j] = 0;
    __syncthreads();
    int base = blockIdx.x * BCHUNK;
    int d[8], sv[8];
#pragma unroll
    for (int k = 0; k < 8; ++k) {
        int i = base + k * 512 + tid;
        bool ok = i < n_edges;
        d[k]  = ok ? dst[i] : -1;
        sv[k] = ok ? src[i] : 0;
        if (ok) atomicAdd(&h[d[k] >> BSH], 1);
    }
    __syncthreads();
    for (int j = tid; j < nb; j += 512) {
        int c = h[j];
        if (c) h[j] = atomicAdd(&gcur[j], c);   // count -> global write base
    }
    __syncthreads();
#pragma unroll
    for (int k = 0; k < 8; ++k) {
        if (d[k] >= 0) {
            int p = atomicAdd(&h[d[k] >> BSH], 1);
            pairs[p] = (uint)sv[k] | ((uint)(d[k] & (BNODES - 1)) << 27);
        }
    }
}

// ---------------------------------------------------------------------------
// Fused aggregate + MFMA GEMM. Block = 32 nodes = 1 bucket, 256 threads.
// Bucket's edges are CONTIGUOUS in pairs[]: coalesced tile load into regs,
// node-histogram, scatter to LDS (pre-scaled byte offsets), 16-deep gather,
// MFMA epilogue. No binary search, no run bookkeeping.
// ---------------------------------------------------------------------------
__global__ __launch_bounds__(256, 6) void agg_gemm_kernel(
    const ushort* __restrict__ xbf, const uint* __restrict__ pairs,
    const int* __restrict__ gbase,
    const ushort* __restrict__ w1, const ushort* __restrict__ w2,
    const float* __restrict__ bias, float* __restrict__ out, int n_nodes)
{
    __shared__ uint sorted[TILE];               // 8 KB (byte offsets, src<<8)
    __shared__ uint abuf[BNODES * ASTRIDE];     // 8.7 KB
    __shared__ int hcnt[BNODES];
    __shared__ int hoff[BNODES + 1];
    __shared__ int hcur[BNODES];

    int blk   = blockIdx.x;      // == bucket index
    int node0 = blk * BNODES;
    int wave  = threadIdx.x >> 6;
    int lane  = threadIdx.x & 63;

    int start = gbase[blk];
    int end   = gbase[blk + 1];

    const char* xu = (const char*)xbf;
    uint lane4 = (uint)lane << 2;

    float2 acc[8];
#pragma unroll
    for (int i = 0; i < 8; ++i) acc[i] = make_float2(0.f, 0.f);

    for (int t0 = start; t0 < end; t0 += TILE) {
        int cnt = end - t0; if (cnt > TILE) cnt = TILE;

        if (threadIdx.x < BNODES) hcnt[threadIdx.x] = 0;
        __syncthreads();

        // pass A: coalesced read into registers + node histogram
        uint pk_[8];
#pragma unroll
        for (int k = 0; k < 8; ++k) {
            int i = threadIdx.x + k * 256;
            if (i < cnt) {
                uint pk = pairs[t0 + i];
                pk_[k] = pk;
                atomicAdd(&hcnt[pk >> 27], 1);
            }
        }
        __syncthreads();

        // 32-entry exclusive scan by wave 0 via shfl
        if (threadIdx.x < 64) {
            int v = (lane < BNODES) ? hcnt[lane] : 0;
#pragma unroll
            for (int off = 1; off < BNODES; off <<= 1) {
                int u = __shfl_up(v, off);
                if (lane >= off) v += u;
            }
            if (lane < BNODES) {
                hoff[lane + 1] = v;
                hcur[lane] = v - hcnt[lane];
            }
            if (lane == 0) hoff[0] = 0;
        }
        __syncthreads();

        // pass B: scatter pre-scaled row byte-offsets, node-sorted
#pragma unroll
        for (int k = 0; k < 8; ++k) {
            int i = threadIdx.x + k * 256;
            if (i < cnt) {
                uint pk = pk_[k];
                int p = atomicAdd(&hcur[pk >> 27], 1);
                sorted[p] = (pk & SRCMASK) << 8;   // byte offset of 256B row
            }
        }
        __syncthreads();

        // wave owns nodes wave*8 .. wave*8+7; 16-deep independent gathers
#pragma unroll
        for (int i = 0; i < 8; ++i) {
            int nl = wave * 8 + i;
            int j0 = hoff[nl], j1 = hoff[nl + 1];
            float2 a = acc[i];
            int j = j0;
            for (; j + 15 < j1; j += 16) {
                uint u[16];
#pragma unroll
                for (int k = 0; k < 16; ++k)
                    u[k] = *(const uint*)(xu + (size_t)(sorted[j + k] + lane4));
#pragma unroll
                for (int k = 0; k < 16; ++k) {
                    a.x += __uint_as_float(u[k] << 16);
                    a.y += __uint_as_float(u[k] & 0xffff0000u);
                }
            }
            for (; j + 3 < j1; j += 4) {
                uint u0 = *(const uint*)(xu + (size_t)(sorted[j + 0] + lane4));
                uint u1 = *(const uint*)(xu + (size_t)(sorted[j + 1] + lane4));
                uint u2 = *(const uint*)(xu + (size_t)(sorted[j + 2] + lane4));
                uint u3 = *(const uint*)(xu + (size_t)(sorted[j + 3] + lane4));
                a.x += __uint_as_float(u0 << 16) + __uint_as_float(u1 << 16)
                     + __uint_as_float(u2 << 16) + __uint_as_float(u3 << 16);
                a.y += __uint_as_float(u0 & 0xffff0000u) + __uint_as_float(u1 & 0xffff0000u)
                     + __uint_as_float(u2 & 0xffff0000u) + __uint_as_float(u3 & 0xffff0000u);
            }
            for (; j < j1; ++j) {
                uint u = *(const uint*)(xu + (size_t)(sorted[j] + lane4));
                a.x += __uint_as_float(u << 16);
                a.y += __uint_as_float(u & 0xffff0000u);
            }
            acc[i] = a;
        }
        __syncthreads();   // protect sorted/hist before next tile
    }

    // stage aggregated rows as bf16 into LDS (row stride 68 uints)
#pragma unroll
    for (int i = 0; i < 8; ++i) {
        int nl = wave * 8 + i;
        abuf[nl * ASTRIDE + lane] =
            (uint)f2bf(acc[i].x) | ((uint)f2bf(acc[i].y) << 16);
    }
    __syncthreads();

    // ---- MFMA phase: 2 waves per 16-row group; each does 4 of 8 o-tiles ----
    int quad = lane >> 4;
    int m    = lane & 15;
    int rg   = wave >> 1;          // row group 0..1
    int half = wave & 1;           // which 4 o-tiles
    int rowL = rg * 16 + m;
    int rowG = node0 + rowL;
    int rowC = (rowG < n_nodes) ? rowG : (n_nodes - 1);   // clamp loads

    short8 xa[4], aa[4];
#pragma unroll
    for (int ks = 0; ks < 4; ++ks) {
        xa[ks] = *reinterpret_cast<const short8*>(xbf + (size_t)rowC * DF + ks * 32 + quad * 8);
        aa[ks] = *reinterpret_cast<const short8*>(&abuf[rowL * ASTRIDE + ks * 16 + quad * 4]);
    }

    int nbase = node0 + rg * 16;
#pragma unroll
    for (int oi = 0; oi < 4; ++oi) {
        int ot = half * 4 + oi;
        int o = ot * 16 + m;
        floatx4 c = {0.f, 0.f, 0.f, 0.f};
#pragma unroll
        for (int ks = 0; ks < 4; ++ks) {
            short8 bf1 = *reinterpret_cast<const short8*>(w1 + (size_t)o * DF + ks * 32 + quad * 8);
            short8 bf2 = *reinterpret_cast<const short8*>(w2 + (size_t)o * DF + ks * 32 + quad * 8);
            c = __builtin_amdgcn_mfma_f32_16x16x32_bf16(xa[ks], bf1, c, 0, 0, 0);
            c = __builtin_amdgcn_mfma_f32_16x16x32_bf16(aa[ks], bf2, c, 0, 0, 0);
        }
        float bv = bias[o];
#pragma unroll
        for (int r = 0; r < 4; ++r) {
            int row = nbase + quad * 4 + r;
            if (row < n_nodes) out[(size_t)row * DF + o] = c[r] + bv;
        }
    }
}

extern "C" void kernel_launch(void* const* d_in, const int* in_sizes, int n_in,
                              void* d_out, int out_size, void* d_ws, size_t ws_size,
                              hipStream_t stream) {
    const float* x  = (const float*)d_in[0];
    const float* W1 = (const float*)d_in[1];
    const float* b1 = (const float*)d_in[2];
    const float* W2 = (const float*)d_in[3];
    const float* b2 = (const float*)d_in[4];
    const int* esrc = (const int*)d_in[5];
    const int* edst = (const int*)d_in[6];
    float* out = (float*)d_out;

    int n_nodes = in_sizes[0] / DF;
    int n_edges = in_sizes[5];

    int nb = (n_nodes + BNODES - 1) >> BSH;       // buckets (1563)
    int PH = (n_edges + PCHUNK - 1) / PCHUNK;     // hist blocks (98)
    int BB = (n_edges + BCHUNK - 1) / BCHUNK;     // bin blocks (196)

    char* ws = (char*)d_ws;
    ushort* xbf   = (ushort*)ws;                 ws += (size_t)n_nodes * DF * 2;
    ushort* w1bf  = (ushort*)ws;                 ws += (size_t)DF * DF * 2;
    ushort* w2bf  = (ushort*)ws;                 ws += (size_t)DF * DF * 2;
    float*  bias  = (float*)ws;                  ws += (size_t)DF * 4;
    int*    ghist = (int*)ws;                    ws += (size_t)(nb + 1) * 4;  // + done
    int*    done  = ghist + nb;
    int*    gbase = (int*)ws;                    ws += (size_t)(nb + 1) * 4;
    int*    gcur  = (int*)ws;                    ws += (size_t)nb * 4;
    uint*   pairs = (uint*)ws;

    // zero ghist[nb] + done (contiguous) each replay
    hipMemsetAsync(ghist, 0, (size_t)(nb + 1) * sizeof(int), stream);

    int n4 = n_nodes * DF / 4;
    int prep_blocks = PH + 64 + (n4 + 255) / 256;
    prep_kernel<<<prep_blocks, 256, 0, stream>>>(
        x, xbf, n4, W1, W2, b1, b2, w1bf, w2bf, bias,
        edst, ghist, done, gbase, gcur, n_edges, PH, nb);

    bin_kernel<<<BB, 512, 0, stream>>>(esrc, edst, gcur, pairs, n_edges, nb);

    agg_gemm_kernel<<<nb, 256, 0, stream>>>(
        xbf, pairs, gbase, w1bf, w2bf, bias, out, n_nodes);
}